// Round 1
// baseline (154.258 us; speedup 1.0000x reference)
//
#include <hip/hip_runtime.h>

namespace {

constexpr int   kC      = 9;
constexpr int   kH      = 80;
constexpr int   kHid    = 100;
constexpr float kNeg    = 0.1f;
constexpr int   kB      = 16;
constexpr int   kBase   = 2 * kH;        // 160 (p,x) slots per group
constexpr int   kVoxLoc = kC * kBase;    // 1440 voxels per batch group

// Histogram scheme (round 9): voxel = sum_e t*g_bin(t) depends on t only ->
// per-block u16 count histogram over (base, t-cell) needs ONE ds_add_u32 per
// event (vs 3 ds_add_u64).  Stochastic cell rounding (unbiased dither) makes
// E[T[c]] the exact lerp of f(t) = t*g_bin(t) at Delta_t = 1/192.
constexpr int   kK      = 192;           // t-cells over [0,1); nodes 0..192
constexpr int   kTPts   = (kK + 1) * kC; // 1737 MLP eval points
constexpr int   kTPadRows = 200;         // T rows incl. pad (uint4 tail reads c<=199)
constexpr int   kWordsPerRow = 100;      // 200 u16 cells = 100 u32 (400 B, 16B-aligned)
constexpr int   kThreads = 1024;
constexpr int   kBlocksPerGroup = 32;

// Fused prep-kernel block split: first kZeroBlocks zero d_out, rest build T.
constexpr int kZeroBlocks  = 90;              // 90*256 = 23040 = out elements
constexpr int kTableBlocks = (kTPts + 3) / 4; // 435: 4 waves/block, 1 point/wave

__device__ __forceinline__ float lrelu(float z) { return z >= 0.f ? z : kNeg * z; }

} // namespace

// Blocks [0, kZeroBlocks) zero d_out; the rest evaluate the MLP at the 1737
// (cell, bin) nodes: T[c*9+bin] = (c/192) * mlp(c/192 - bin/8).  One wave per
// point; lane owns hidden column `lane` (+64+lane for lanes<36); W2 rows
// coalesced; shuffle-reduce.  Wave 0 also zeroes the 63 pad entries
// (rows 193..199) so the flush's uint4 tail reads finite values (0*cnt==0).
__global__ __launch_bounds__(256) void prep_kernel(
    const float* __restrict__ W1, const float* __restrict__ b1,
    const float* __restrict__ W2, const float* __restrict__ b2,
    const float* __restrict__ W3, const float* __restrict__ b3,
    float* __restrict__ T, float* __restrict__ out, int out_n) {
  if (blockIdx.x < kZeroBlocks) {
    int i = blockIdx.x * 256 + threadIdx.x;
    if (i < out_n) out[i] = 0.f;
    return;
  }
  int wave = ((blockIdx.x - kZeroBlocks) * 256 + (int)threadIdx.x) >> 6;
  int lane = threadIdx.x & 63;
  if (wave >= kTPts) return;
  if (wave == 0 && lane < kTPadRows * kC - kTPts)   // 1800-1737 = 63 pad floats
    T[kTPts + lane] = 0.f;

  int c   = wave / kC;
  int bin = wave - kC * c;                 // wave = c*9 + bin
  float tc = (float)c * (1.0f / (float)kK);
  float ts = tc - 0.125f * (float)bin;     // t - bin/(C-1)

  bool two = (lane < kHid - 64);
  float acc1 = 0.f, acc2 = 0.f;
  for (int j = 0; j < kHid; ++j) {
    float h1 = lrelu(fmaf(ts, W1[j], b1[j]));
    const float* row = W2 + j * kHid;
    acc1 = fmaf(h1, row[lane], acc1);
    float w2b = two ? row[64 + lane] : 0.f;
    acc2 = fmaf(h1, w2b, acc2);
  }
  float o = lrelu(acc1 + b2[lane]) * W3[lane];
  if (two) o += lrelu(acc2 + b2[64 + lane]) * W3[64 + lane];
#pragma unroll
  for (int off = 32; off >= 1; off >>= 1) o += __shfl_xor(o, off);
  if (lane == 0) T[wave] = tc * (o + b3[0]);
}

// Measured model (rounds 1-8): LDS atomics ~3.3 cyc/lane/instruction,
// invariant to width/banks/occupancy -> instruction COUNT is the only knob.
// Round 9 drops 3 ds_add_u64/event to 1 ds_add_u32/event via a count
// histogram; u16 fields are unconditionally overflow-safe (<=3907 events per
// block < 65536).  Flush: item = base*9+bin so 9 consecutive lanes broadcast
// the same hist row (ds_read_b128, distinct banks across bases; row stride
// 400 B is 16B-aligned); T reads are L1-resident (7.2 KB, 9-lane coalesced).
__global__ __launch_bounds__(kThreads) void scatter_kernel(
    const float4* __restrict__ events, const float* __restrict__ T,
    float* __restrict__ out, int Ngroup) {
  __shared__ unsigned s_hist[kBase * kWordsPerRow];   // 64,000 B -> 2 blocks/CU
  for (int i = threadIdx.x; i < kBase * kWordsPerRow; i += kThreads)
    s_hist[i] = 0u;
  __syncthreads();

  int g   = blockIdx.x / kBlocksPerGroup;
  int sub = blockIdx.x % kBlocksPerGroup;
  int per = (Ngroup + kBlocksPerGroup - 1) / kBlocksPerGroup;
  int start = g * Ngroup + sub * per;
  int end   = g * Ngroup + min((sub + 1) * per, Ngroup);

  for (int i = start + (int)threadIdx.x; i < end; i += kThreads) {
    float4 e = events[i];                       // (x, t, p, b)
    int base = (int)e.z * kH + (int)e.x - 1;    // p*80 + (x-1), in [0,160)
    // per-event dither in [0,1): Knuth multiplicative hash of event index;
    // c = floor(t*192 + dith) is unbiased stochastic rounding -> E = lerp.
    float dith = (float)((unsigned)i * 2654435761u >> 8) * (1.0f / 16777216.0f);
    int c = (int)fmaf(e.y, (float)kK, dith);    // in [0, 192]
    c = min(max(c, 0), kK);                     // defensive
    atomicAdd(&s_hist[base * kWordsPerRow + (c >> 1)], 1u << ((c & 1) << 4));
  }
  __syncthreads();

  float* og = out + g * kVoxLoc;
  for (int it = threadIdx.x; it < kVoxLoc; it += kThreads) {
    int base = it / kC;
    int bin  = it - kC * base;
    const uint4* row =
        reinterpret_cast<const uint4*>(&s_hist[base * kWordsPerRow]);
    const float* Tb = T + bin;
    float acc = 0.f;
    for (int q = 0; q < kWordsPerRow / 4; ++q) {   // 25 x ds_read_b128
      uint4 w = row[q];
      int c0 = q * 8;
      acc = fmaf((float)(w.x & 0xFFFFu), Tb[(c0 + 0) * kC], acc);
      acc = fmaf((float)(w.x >> 16),     Tb[(c0 + 1) * kC], acc);
      acc = fmaf((float)(w.y & 0xFFFFu), Tb[(c0 + 2) * kC], acc);
      acc = fmaf((float)(w.y >> 16),     Tb[(c0 + 3) * kC], acc);
      acc = fmaf((float)(w.z & 0xFFFFu), Tb[(c0 + 4) * kC], acc);
      acc = fmaf((float)(w.z >> 16),     Tb[(c0 + 5) * kC], acc);
      acc = fmaf((float)(w.w & 0xFFFFu), Tb[(c0 + 6) * kC], acc);
      acc = fmaf((float)(w.w >> 16),     Tb[(c0 + 7) * kC], acc);
    }
    atomicAdd(&og[bin * kBase + base], acc * 0.01f);
  }
}

extern "C" void kernel_launch(void* const* d_in, const int* in_sizes, int n_in,
                              void* d_out, int out_size, void* d_ws, size_t ws_size,
                              hipStream_t stream) {
  const float4* events = (const float4*)d_in[0];
  const float* W1 = (const float*)d_in[1];
  const float* b1 = (const float*)d_in[2];
  const float* W2 = (const float*)d_in[3];
  const float* b2 = (const float*)d_in[4];
  const float* W3 = (const float*)d_in[5];
  const float* b3 = (const float*)d_in[6];
  float* out = (float*)d_out;
  float* T   = (float*)d_ws;                  // 1800 floats = 7.2 KB

  int N = in_sizes[0] / 4;
  int Ngroup = N / kB;

  prep_kernel<<<kZeroBlocks + kTableBlocks, 256, 0, stream>>>(
      W1, b1, W2, b2, W3, b3, T, out, out_size);
  scatter_kernel<<<kB * kBlocksPerGroup, kThreads, 0, stream>>>(
      events, T, out, Ngroup);
}

// Round 2
// 122.466 us; speedup vs baseline: 1.2596x; 1.2596x over previous
//
#include <hip/hip_runtime.h>

namespace {

constexpr int   kC      = 9;
constexpr int   kH      = 80;
constexpr int   kHid    = 100;
constexpr float kNeg    = 0.1f;
constexpr int   kB      = 16;
constexpr int   kBase   = 2 * kH;        // 160 (p,x) slots per group
constexpr int   kVoxLoc = kC * kBase;    // 1440 voxels per batch group

// Histogram scheme (round 9/10): voxel = sum_e t*g_bin(t) depends on t only
// -> per-block u16 count histogram over (base, t-cell): ONE ds_add_u32 per
// event.  Stochastic cell rounding (unbiased dither) makes E equal the exact
// lerp of f(t) = t*g_bin(t) at Delta_t = 1/192 (measured absmax 1.95e-3).
// Round 10 fix: round 9's per-block dot-product flush was 32x-redundant per
// group and latency-serialized (VGPR=16, 25 non-unrolled ds_read+8 strided
// loads per output) -> scatter 72us.  Counts are additive: flush raw u32
// words to a per-GROUP global hist (zero-skip, ~3.5k atomics/block), then
// ONE tiny matmul kernel (16x160x193x9 = 4.4M MACs) produces out with plain
// stores (no out zero-init, no f32 atomics, exact integer accumulation).
constexpr int   kK      = 192;           // t-cells over [0,1]; nodes 0..192
constexpr int   kTPts   = (kK + 1) * kC; // 1737 MLP eval points
constexpr int   kTPad   = 1800;          // T floats incl. pad (uint4 tail)
constexpr int   kWordsPerRow = 100;      // 200 u16 cells = 100 u32 (400 B)
constexpr int   kHistWords   = kBase * kWordsPerRow;  // 16000 per group
constexpr int   kThreads = 1024;
constexpr int   kBlocksPerGroup = 32;
constexpr size_t kHistOff = 8192;        // ghist byte offset in d_ws

// prep block split: first kZeroBlocks zero ghist (256000 u32 as 64000 uint4,
// 32000 threads x 2), rest build T.
constexpr int kZeroBlocks  = 125;
constexpr int kTableBlocks = (kTPts + 3) / 4;  // 435: 4 waves/block

__device__ __forceinline__ float lrelu(float z) { return z >= 0.f ? z : kNeg * z; }

} // namespace

// Blocks [0, kZeroBlocks) zero ghist; the rest evaluate the MLP at the 1737
// (cell, bin) nodes: T[c*9+bin] = (c/192) * mlp(c/192 - bin/8).  One wave per
// point; lane owns hidden column `lane` (+64+lane for lanes<36); W2 rows
// coalesced; shuffle-reduce.  Wave 0 zeroes the 63 pad floats (T[1737..1799])
// so finish's uint4 tail (cells 193..199, count 0) reads finite values.
__global__ __launch_bounds__(256) void prep_kernel(
    const float* __restrict__ W1, const float* __restrict__ b1,
    const float* __restrict__ W2, const float* __restrict__ b2,
    const float* __restrict__ W3, const float* __restrict__ b3,
    float* __restrict__ T, uint4* __restrict__ ghist4) {
  if (blockIdx.x < kZeroBlocks) {
    int i = blockIdx.x * 256 + (int)threadIdx.x;   // 0..31999
    uint4 z = make_uint4(0u, 0u, 0u, 0u);
    ghist4[i] = z;
    ghist4[i + 32000] = z;
    return;
  }
  int wave = ((blockIdx.x - kZeroBlocks) * 256 + (int)threadIdx.x) >> 6;
  int lane = threadIdx.x & 63;
  if (wave >= kTPts) return;
  if (wave == 0 && lane < kTPad - kTPts)   // 63 pad floats
    T[kTPts + lane] = 0.f;

  int c   = wave / kC;
  int bin = wave - kC * c;                 // wave = c*9 + bin
  float tc = (float)c * (1.0f / (float)kK);
  float ts = tc - 0.125f * (float)bin;     // t - bin/(C-1)

  bool two = (lane < kHid - 64);
  float acc1 = 0.f, acc2 = 0.f;
  for (int j = 0; j < kHid; ++j) {
    float h1 = lrelu(fmaf(ts, W1[j], b1[j]));
    const float* row = W2 + j * kHid;
    acc1 = fmaf(h1, row[lane], acc1);
    float w2b = two ? row[64 + lane] : 0.f;
    acc2 = fmaf(h1, w2b, acc2);
  }
  float o = lrelu(acc1 + b2[lane]) * W3[lane];
  if (two) o += lrelu(acc2 + b2[64 + lane]) * W3[64 + lane];
#pragma unroll
  for (int off = 32; off >= 1; off >>= 1) o += __shfl_xor(o, off);
  if (lane == 0) T[wave] = tc * (o + b3[0]);
}

// Main loop: 1 ds_add_u32 per event (measured LDS-atomic model: 3.3
// cyc/lane/instruction, count-invariant -> ~10.7us floor for 2M events).
// Flush: raw u32 words to the group's global hist, zero-skipped (~78% of
// words empty at 0.24 events/cell/block), coalesced fire-and-forget
// global_atomic_add.  u16 fields exact: per-(group,base,cell) ~4 events avg.
__global__ __launch_bounds__(kThreads) void scatter_kernel(
    const float4* __restrict__ events, unsigned* __restrict__ ghist,
    int Ngroup) {
  __shared__ unsigned s_hist[kHistWords];   // 64,000 B -> 2 blocks/CU
  for (int i = threadIdx.x; i < kHistWords; i += kThreads) s_hist[i] = 0u;
  __syncthreads();

  int g   = blockIdx.x / kBlocksPerGroup;
  int sub = blockIdx.x % kBlocksPerGroup;
  int per = (Ngroup + kBlocksPerGroup - 1) / kBlocksPerGroup;
  int start = g * Ngroup + sub * per;
  int end   = g * Ngroup + min((sub + 1) * per, Ngroup);

  for (int i = start + (int)threadIdx.x; i < end; i += kThreads) {
    float4 e = events[i];                       // (x, t, p, b)
    int base = (int)e.z * kH + (int)e.x - 1;    // p*80 + (x-1), in [0,160)
    // per-event dither in [0,1): Knuth hash of event index; c =
    // floor(t*192 + dith) is unbiased stochastic rounding -> E = lerp.
    float dith = (float)((unsigned)i * 2654435761u >> 8) * (1.0f / 16777216.0f);
    int c = (int)fmaf(e.y, (float)kK, dith);    // in [0, 192]
    c = min(max(c, 0), kK);                     // defensive
    atomicAdd(&s_hist[base * kWordsPerRow + (c >> 1)], 1u << ((c & 1) << 4));
  }
  __syncthreads();

  unsigned* gh = ghist + g * kHistWords;
  for (int i = threadIdx.x; i < kHistWords; i += kThreads) {
    unsigned v = s_hist[i];
    if (v) atomicAdd(&gh[i], v);
  }
}

// One thread per output voxel: out[g][bin][base] = 0.01 * sum_c
// hist[g][base][c] * T[c*9+bin].  9 consecutive lanes share a hist row
// (broadcast uint4 loads, L2-resident 1 MB) and read 9 consecutive T floats
// (L1-resident 7.2 KB).  Plain store -> no zero-init, no atomics, exact.
__global__ __launch_bounds__(256) void finish_kernel(
    const unsigned* __restrict__ ghist, const float* __restrict__ T,
    float* __restrict__ out) {
  int tid = blockIdx.x * 256 + (int)threadIdx.x;
  if (tid >= kB * kVoxLoc) return;
  int g = tid / kVoxLoc;
  int r = tid - g * kVoxLoc;
  int base = r / kC;
  int bin  = r - kC * base;
  const uint4* row = reinterpret_cast<const uint4*>(
      ghist + g * kHistWords + base * kWordsPerRow);
  const float* Tb = T + bin;
  float acc = 0.f;
#pragma unroll 5
  for (int q = 0; q < kWordsPerRow / 4; ++q) {   // 25 x uint4
    uint4 w = row[q];
    int c0 = q * 8;
    acc = fmaf((float)(w.x & 0xFFFFu), Tb[(c0 + 0) * kC], acc);
    acc = fmaf((float)(w.x >> 16),     Tb[(c0 + 1) * kC], acc);
    acc = fmaf((float)(w.y & 0xFFFFu), Tb[(c0 + 2) * kC], acc);
    acc = fmaf((float)(w.y >> 16),     Tb[(c0 + 3) * kC], acc);
    acc = fmaf((float)(w.z & 0xFFFFu), Tb[(c0 + 4) * kC], acc);
    acc = fmaf((float)(w.z >> 16),     Tb[(c0 + 5) * kC], acc);
    acc = fmaf((float)(w.w & 0xFFFFu), Tb[(c0 + 6) * kC], acc);
    acc = fmaf((float)(w.w >> 16),     Tb[(c0 + 7) * kC], acc);
  }
  out[g * kVoxLoc + bin * kBase + base] = acc * 0.01f;
}

extern "C" void kernel_launch(void* const* d_in, const int* in_sizes, int n_in,
                              void* d_out, int out_size, void* d_ws, size_t ws_size,
                              hipStream_t stream) {
  const float4* events = (const float4*)d_in[0];
  const float* W1 = (const float*)d_in[1];
  const float* b1 = (const float*)d_in[2];
  const float* W2 = (const float*)d_in[3];
  const float* b2 = (const float*)d_in[4];
  const float* W3 = (const float*)d_in[5];
  const float* b3 = (const float*)d_in[6];
  float* out = (float*)d_out;
  float* T = (float*)d_ws;                                   // 7.2 KB
  unsigned* ghist = (unsigned*)((char*)d_ws + kHistOff);     // 1.024 MB

  int N = in_sizes[0] / 4;
  int Ngroup = N / kB;

  prep_kernel<<<kZeroBlocks + kTableBlocks, 256, 0, stream>>>(
      W1, b1, W2, b2, W3, b3, T, (uint4*)ghist);
  scatter_kernel<<<kB * kBlocksPerGroup, kThreads, 0, stream>>>(
      events, ghist, Ngroup);
  finish_kernel<<<(kB * kVoxLoc + 255) / 256, 256, 0, stream>>>(
      ghist, T, out);
}

// Round 4
// 101.049 us; speedup vs baseline: 1.5266x; 1.2119x over previous
//
#include <hip/hip_runtime.h>

namespace {

constexpr int   kC      = 9;
constexpr int   kH      = 80;
constexpr int   kHid    = 100;
constexpr float kNeg    = 0.1f;
constexpr int   kB      = 16;
constexpr int   kBase   = 2 * kH;        // 160 (p,x) slots per group
constexpr int   kVoxLoc = kC * kBase;    // 1440 voxels per batch group

// Histogram scheme (rounds 9-11): voxel = sum_e t*g_bin(t) depends on t only
// -> per-block u16 count histogram over (base, t-cell): ONE ds_add_u32 per
// event (measured LDS-atomic model: ~3.3 cyc/lane/instruction, count is the
// only knob).  Stochastic cell rounding (unbiased Knuth dither) makes E[]
// the exact lerp of f(t) = t*g_bin(t) at dt = 1/192 (measured absmax
// 1.95e-3, threshold ~5.5e-3).
// Round 11: round 10's global-atomic flush cost ~19us (1.8M u32 L2 atomics
// @ ~95 Gatomic/s).  Counts are additive -> blocks plain-store raw 64KB
// histograms to private parts[sub] planes (coalesced, zeros included, no
// init needed), a reduce kernel sums 16 planes (streaming BW, ~4us), and
// finish does the 16x160x193x9 matmul once with plain stores.  No atomics
// and no zero-init anywhere except T's 63 pad floats (NaN-poison guard).
// Round 12: resubmit after container infra failure; added base clamp so no
// event encoding can produce an LDS OOB write.
constexpr int   kK      = 192;           // t-cells over [0,1]; nodes 0..192
constexpr int   kTPts   = (kK + 1) * kC; // 1737 MLP eval points
constexpr int   kTPad   = 1800;          // T floats incl. pad (uint4 tail)
constexpr int   kWordsPerRow = 100;      // 200 u16 cells = 100 u32 (400 B)
constexpr int   kHistWords   = kBase * kWordsPerRow;  // 16000 u32 (64 KB)
constexpr int   kHistUint4   = kHistWords / 4;        // 4000
constexpr int   kThreads = 1024;
constexpr int   kSubs    = 16;           // scatter blocks per group
constexpr int   kScatBlocks = kB * kSubs;             // 256
constexpr int   kPrepBlocks = (kTPts + 15) / 16;      // 109 (16 waves/block)
constexpr int   kRedUint4   = kB * kHistUint4;        // 64000

// d_ws layout: [0, 7200) T; [8192, +1MB) gh; then 16 MB parts.
constexpr size_t kGhOff    = 8192;
constexpr size_t kPartsOff = kGhOff + (size_t)kB * kHistWords * 4;  // 1032192

__device__ __forceinline__ float lrelu(float z) { return z >= 0.f ? z : kNeg * z; }

} // namespace

// Fused kernel.  Blocks [0, kScatBlocks): per-block LDS count histogram over
// (base, t-cell), then raw 64KB store to parts[sub][g].  Blocks
// [kScatBlocks, +kPrepBlocks): evaluate the MLP at the 1737 (cell, bin)
// nodes, T[c*9+bin] = (c/192)*mlp(c/192 - bin/8) -- one wave per point, lane
// owns hidden col `lane` (+64+lane for lanes<36), W2 rows coalesced,
// shuffle-reduce.  Prep blocks are VALU/global-load bound, scatter blocks
// LDS-atomic bound -> separate pipes co-schedule; stream ordering guarantees
// T completes before finish_kernel launches.
__global__ __launch_bounds__(kThreads) void scatter_kernel(
    const float4* __restrict__ events,
    const float* __restrict__ W1, const float* __restrict__ b1,
    const float* __restrict__ W2, const float* __restrict__ b2,
    const float* __restrict__ W3, const float* __restrict__ b3,
    float* __restrict__ T, unsigned* __restrict__ parts, int Ngroup) {
  if (blockIdx.x >= kScatBlocks) {
    // ---- table-building path ----
    int wave = (blockIdx.x - kScatBlocks) * (kThreads >> 6) +
               ((int)threadIdx.x >> 6);
    int lane = threadIdx.x & 63;
    if (wave == 0 && lane < kTPad - kTPts)   // zero 63 pad floats (poison!)
      T[kTPts + lane] = 0.f;
    if (wave >= kTPts) return;

    int c   = wave / kC;
    int bin = wave - kC * c;                 // wave = c*9 + bin
    float tc = (float)c * (1.0f / (float)kK);
    float ts = tc - 0.125f * (float)bin;     // t - bin/(C-1)

    bool two = (lane < kHid - 64);
    float acc1 = 0.f, acc2 = 0.f;
    for (int j = 0; j < kHid; ++j) {
      float h1 = lrelu(fmaf(ts, W1[j], b1[j]));
      const float* row = W2 + j * kHid;
      acc1 = fmaf(h1, row[lane], acc1);
      float w2b = two ? row[64 + lane] : 0.f;
      acc2 = fmaf(h1, w2b, acc2);
    }
    float o = lrelu(acc1 + b2[lane]) * W3[lane];
    if (two) o += lrelu(acc2 + b2[64 + lane]) * W3[64 + lane];
#pragma unroll
    for (int off = 32; off >= 1; off >>= 1) o += __shfl_xor(o, off);
    if (lane == 0) T[wave] = tc * (o + b3[0]);
    return;
  }

  // ---- scatter path ----
  __shared__ unsigned s_hist[kHistWords] __attribute__((aligned(16)));
  uint4* s4 = reinterpret_cast<uint4*>(s_hist);
  uint4 z4 = make_uint4(0u, 0u, 0u, 0u);
  for (int i = threadIdx.x; i < kHistUint4; i += kThreads) s4[i] = z4;
  __syncthreads();

  int g   = blockIdx.x / kSubs;
  int sub = blockIdx.x % kSubs;
  int per = (Ngroup + kSubs - 1) / kSubs;
  int start = g * Ngroup + sub * per;
  int end   = g * Ngroup + min((sub + 1) * per, Ngroup);

  for (int i = start + (int)threadIdx.x; i < end; i += kThreads) {
    float4 e = events[i];                       // (x, t, p, b)
    int base = (int)e.z * kH + (int)e.x - 1;    // p*80 + (x-1), in [0,160)
    base = min(max(base, 0), kBase - 1);        // LDS OOB guard
    // per-event dither in [0,1): Knuth hash of event index; c =
    // floor(t*192 + dith) is unbiased stochastic rounding -> E = lerp.
    float dith = (float)((unsigned)i * 2654435761u >> 8) * (1.0f / 16777216.0f);
    int c = (int)fmaf(e.y, (float)kK, dith);    // in [0, 192]
    c = min(max(c, 0), kK);                     // defensive
    atomicAdd(&s_hist[base * kWordsPerRow + (c >> 1)], 1u << ((c & 1) << 4));
  }
  __syncthreads();

  uint4* dst = reinterpret_cast<uint4*>(parts) +
               (size_t)sub * (kB * kHistUint4) + g * kHistUint4;
  for (int i = threadIdx.x; i < kHistUint4; i += kThreads) dst[i] = s4[i];
}

// gh[j] = sum over 16 sub-planes (uint4 lanes, perfectly coalesced reads of
// 16 MB, plain 1 MB store).  u16 fields exact: per-(group,base,cell) counts
// are ~Poisson(4) -- nowhere near 65535.
__global__ __launch_bounds__(256) void reduce_kernel(
    const uint4* __restrict__ parts, uint4* __restrict__ gh) {
  int j = blockIdx.x * 256 + (int)threadIdx.x;
  if (j >= kRedUint4) return;
  uint4 a = make_uint4(0u, 0u, 0u, 0u);
#pragma unroll
  for (int s = 0; s < kSubs; ++s) {
    uint4 v = parts[(size_t)s * kRedUint4 + j];
    a.x += v.x; a.y += v.y; a.z += v.z; a.w += v.w;
  }
  gh[j] = a;
}

// One thread per output voxel: out[g][bin][base] = 0.01 * sum_c
// hist[g][base][c] * T[c*9+bin].  9 consecutive lanes share a hist row
// (broadcast uint4 loads, L2-resident 1 MB read 9x) and read 9 consecutive
// T floats (L1-resident 7.2 KB).  Plain store -> no init, no atomics.
// 128-thread blocks -> 180 blocks (round-10's 90 left CUs idle).
__global__ __launch_bounds__(128) void finish_kernel(
    const unsigned* __restrict__ ghist, const float* __restrict__ T,
    float* __restrict__ out) {
  int tid = blockIdx.x * 128 + (int)threadIdx.x;
  if (tid >= kB * kVoxLoc) return;
  int g = tid / kVoxLoc;
  int r = tid - g * kVoxLoc;
  int base = r / kC;
  int bin  = r - kC * base;
  const uint4* row = reinterpret_cast<const uint4*>(
      ghist + g * kHistWords + base * kWordsPerRow);
  const float* Tb = T + bin;
  float acc = 0.f;
#pragma unroll 5
  for (int q = 0; q < kWordsPerRow / 4; ++q) {   // 25 x uint4
    uint4 w = row[q];
    int c0 = q * 8;
    acc = fmaf((float)(w.x & 0xFFFFu), Tb[(c0 + 0) * kC], acc);
    acc = fmaf((float)(w.x >> 16),     Tb[(c0 + 1) * kC], acc);
    acc = fmaf((float)(w.y & 0xFFFFu), Tb[(c0 + 2) * kC], acc);
    acc = fmaf((float)(w.y >> 16),     Tb[(c0 + 3) * kC], acc);
    acc = fmaf((float)(w.z & 0xFFFFu), Tb[(c0 + 4) * kC], acc);
    acc = fmaf((float)(w.z >> 16),     Tb[(c0 + 5) * kC], acc);
    acc = fmaf((float)(w.w & 0xFFFFu), Tb[(c0 + 6) * kC], acc);
    acc = fmaf((float)(w.w >> 16),     Tb[(c0 + 7) * kC], acc);
  }
  out[g * kVoxLoc + bin * kBase + base] = acc * 0.01f;
}

extern "C" void kernel_launch(void* const* d_in, const int* in_sizes, int n_in,
                              void* d_out, int out_size, void* d_ws, size_t ws_size,
                              hipStream_t stream) {
  const float4* events = (const float4*)d_in[0];
  const float* W1 = (const float*)d_in[1];
  const float* b1 = (const float*)d_in[2];
  const float* W2 = (const float*)d_in[3];
  const float* b2 = (const float*)d_in[4];
  const float* W3 = (const float*)d_in[5];
  const float* b3 = (const float*)d_in[6];
  float* out = (float*)d_out;
  float* T = (float*)d_ws;                                    // 7.2 KB
  unsigned* gh    = (unsigned*)((char*)d_ws + kGhOff);        // 1.024 MB
  unsigned* parts = (unsigned*)((char*)d_ws + kPartsOff);     // 16.384 MB

  int N = in_sizes[0] / 4;
  int Ngroup = N / kB;

  scatter_kernel<<<kScatBlocks + kPrepBlocks, kThreads, 0, stream>>>(
      events, W1, b1, W2, b2, W3, b3, T, parts, Ngroup);
  reduce_kernel<<<(kRedUint4 + 255) / 256, 256, 0, stream>>>(
      (const uint4*)parts, (uint4*)gh);
  finish_kernel<<<(kB * kVoxLoc + 127) / 128, 128, 0, stream>>>(
      gh, T, out);
}